// Round 14
// baseline (1073.385 us; speedup 1.0000x reference)
//
#include <hip/hip_runtime.h>
#include <hip/hip_cooperative_groups.h>
#include <math.h>

namespace cg = cooperative_groups;
typedef unsigned long long u64;

#define NN 4096
#define LBL 343
#define PSTRIDE 344   // ptrbuf row stride (u16), even => aligned u32 pair stores
#define APITCH 344    // padded A row stride (floats); 344*4B = 1376 ≡ 0 mod 16
#define U64MAX 0xFFFFFFFFFFFFFFFFull
#define MST_ROUNDS 12 // components at least halve per round: 2^12 = 4096
#define TAU 0.05f     // candidate threshold; exactness guarded by fallback
#define CANDCAP 96

// ---------------------------------------------------------------------------
// Init: identity components, minE parity buffers, counters, Apad build.
// ---------------------------------------------------------------------------
__global__ void mrf_init_kernel(const float* __restrict__ A, float* __restrict__ Apad,
                                int* __restrict__ compA,
                                u64* __restrict__ minEa, u64* __restrict__ minEb,
                                int* __restrict__ counters)
{
  const int id = blockIdx.x * 256 + threadIdx.x;
  if (id < NN) { compA[id] = id; minEa[id] = U64MAX; minEb[id] = U64MAX; }
  if (id == 0) { counters[0] = NN; counters[1] = NN; counters[2] = 0; }
  if (id < LBL * APITCH) {
    const int r = id / APITCH;
    const int c = id - r * APITCH;
    Apad[id] = (c < LBL) ? A[r * LBL + c] : 0.0f;
  }
}

// ---------------------------------------------------------------------------
// Boruvka round 0: full per-row scan (one wave per row) -> min outgoing edge
// via block dedupe + atomicMin, AND compact per-row candidate shortlist of
// edges with w < TAU (cap CANDCAP; order-free, consumer takes a min).
// ---------------------------------------------------------------------------
__global__ __launch_bounds__(1024) void mrf_scan0_kernel(
    const float* __restrict__ dist, const int* __restrict__ compR,
    u64* __restrict__ minE, int* __restrict__ counters,
    u64* __restrict__ cand, int* __restrict__ candCnt)
{
  __shared__ int s_cc[16];
  __shared__ u64 s_cv[16];
  __shared__ int s_cnt[16];

  if (blockIdx.x == 0 && threadIdx.x == 0) counters[0] = 0;

  const int i    = (blockIdx.x * 1024 + threadIdx.x) >> 6;  // row 0..4095
  const int lane = threadIdx.x & 63;
  const int wib  = threadIdx.x >> 6;
  if (lane == 0) s_cnt[wib] = 0;
  __syncthreads();

  const int ci = compR[i];
  const float4* rowp = (const float4*)(dist + (size_t)i * NN);
  const int4* cp = (const int4*)compR;
  u64 best = U64MAX;
  #pragma unroll 2
  for (int k = 0; k < 16; ++k) {
    const int q = k * 64 + lane;
    const float4 dv = rowp[q];
    const int4 cv = cp[q];
    const int j0 = q * 4;
    if (cv.x != ci) {
      const u64 p = ((u64)__float_as_uint(dv.x) << 24) | ((u64)i << 12) | (u64)(j0    );
      best = best < p ? best : p;
      if (dv.x < TAU) { const int s = atomicAdd(&s_cnt[wib], 1); if (s < CANDCAP) cand[(size_t)i * CANDCAP + s] = p; }
    }
    if (cv.y != ci) {
      const u64 p = ((u64)__float_as_uint(dv.y) << 24) | ((u64)i << 12) | (u64)(j0 + 1);
      best = best < p ? best : p;
      if (dv.y < TAU) { const int s = atomicAdd(&s_cnt[wib], 1); if (s < CANDCAP) cand[(size_t)i * CANDCAP + s] = p; }
    }
    if (cv.z != ci) {
      const u64 p = ((u64)__float_as_uint(dv.z) << 24) | ((u64)i << 12) | (u64)(j0 + 2);
      best = best < p ? best : p;
      if (dv.z < TAU) { const int s = atomicAdd(&s_cnt[wib], 1); if (s < CANDCAP) cand[(size_t)i * CANDCAP + s] = p; }
    }
    if (cv.w != ci) {
      const u64 p = ((u64)__float_as_uint(dv.w) << 24) | ((u64)i << 12) | (u64)(j0 + 3);
      best = best < p ? best : p;
      if (dv.w < TAU) { const int s = atomicAdd(&s_cnt[wib], 1); if (s < CANDCAP) cand[(size_t)i * CANDCAP + s] = p; }
    }
  }
  #pragma unroll
  for (int sh = 32; sh >= 1; sh >>= 1) {
    const u64 o = __shfl_down(best, sh);
    best = best < o ? best : o;
  }
  if (lane == 0) {
    s_cc[wib] = (best == U64MAX) ? -1 : ci;
    s_cv[wib] = best;
    candCnt[i] = s_cnt[wib];            // >CANDCAP => consumer full-rescans
  }
  __syncthreads();
  if (threadIdx.x == 0) {
    for (int a = 0; a < 16; ++a) {
      const int c = s_cc[a];
      if (c < 0) continue;
      bool dup = false;
      for (int b2 = 0; b2 < a; ++b2) if (s_cc[b2] == c) { dup = true; break; }
      if (dup) continue;
      u64 b = s_cv[a];
      for (int b2 = a + 1; b2 < 16; ++b2)
        if (s_cc[b2] == c && s_cv[b2] < b) b = s_cv[b2];
      atomicMin(&minE[c & (NN - 1)], b);
    }
  }
}

// ---------------------------------------------------------------------------
// Boruvka rounds >=1: per-row min outgoing edge from the candidate shortlist
// (one thread per row). If no candidate crosses components (or the list
// overflowed), fall back to an exact full row rescan -- so the result is
// ALWAYS the true row minimum outgoing edge.
// ---------------------------------------------------------------------------
__global__ __launch_bounds__(256) void mrf_scanc_kernel(
    const float* __restrict__ dist, const int* __restrict__ compR,
    u64* __restrict__ minE, int* __restrict__ counters, int round,
    const u64* __restrict__ cand, const int* __restrict__ candCnt)
{
  if (blockIdx.x == 0 && threadIdx.x == 0) counters[round & 1] = 0;
  if (counters[(round - 1) & 1] <= 1) return;

  const int i = blockIdx.x * 256 + threadIdx.x;   // 16 blocks x 256 = 4096
  const int ci = compR[i];
  u64 best = U64MAX;
  const int n = candCnt[i];
  if (n <= CANDCAP) {
    for (int k = 0; k < n; ++k) {
      const u64 e = cand[(size_t)i * CANDCAP + k];
      const int j = (int)(e & 0xFFF);
      if (compR[j] != ci) best = best < e ? best : e;
    }
  }
  if (best == U64MAX) {
    // rare exact fallback: full row rescan
    const float4* rowp = (const float4*)(dist + (size_t)i * NN);
    const int4* cp = (const int4*)compR;
    for (int q = 0; q < NN / 4; ++q) {
      const float4 dv = rowp[q];
      const int4 cv = cp[q];
      const int j0 = q * 4;
      if (cv.x != ci) { const u64 p = ((u64)__float_as_uint(dv.x) << 24) | ((u64)i << 12) | (u64)(j0    ); best = best < p ? best : p; }
      if (cv.y != ci) { const u64 p = ((u64)__float_as_uint(dv.y) << 24) | ((u64)i << 12) | (u64)(j0 + 1); best = best < p ? best : p; }
      if (cv.z != ci) { const u64 p = ((u64)__float_as_uint(dv.z) << 24) | ((u64)i << 12) | (u64)(j0 + 2); best = best < p ? best : p; }
      if (cv.w != ci) { const u64 p = ((u64)__float_as_uint(dv.w) << 24) | ((u64)i << 12) | (u64)(j0 + 3); best = best < p ? best : p; }
    }
  }
  if (best != U64MAX) atomicMin(&minE[ci & (NN - 1)], best);
}

// ---------------------------------------------------------------------------
// Boruvka phases 2+3 fused (unchanged, passing).
// ---------------------------------------------------------------------------
__global__ __launch_bounds__(1024) void mrf_hook_kernel(
    const int* __restrict__ compR, int* __restrict__ compW,
    const u64* __restrict__ minE, u64* __restrict__ minEnext,
    int* __restrict__ eu, int* __restrict__ ev, unsigned* __restrict__ ew,
    int* __restrict__ counters, int round)
{
  if (round > 0 && counters[(round - 1) & 1] <= 1) return;
  const int i = blockIdx.x * 1024 + threadIdx.x;
  if (i >= NN) return;
  minEnext[i] = U64MAX;

  const int r0 = compR[i];
  int cur = r0;
  for (int guard = 0; guard < NN + 2; ++guard) {
    const u64 e = minE[cur];
    if (e == U64MAX) break;
    const int v = (int)(e & 0xFFF);
    const int t = compR[v];
    if (t == cur) break;
    const u64 te = minE[t];
    if (te != U64MAX) {
      const int tv = (int)(te & 0xFFF);
      if (compR[tv] == cur && cur < t) break;    // mutual pair: cur wins
    }
    cur = t;
  }
  compW[i] = cur;
  if (cur == i) atomicAdd(&counters[round & 1], 1);

  if (r0 == i) {
    const u64 e = minE[i];
    if (e != U64MAX) {
      const int v = (int)(e & 0xFFF);
      const int u = (int)((e >> 12) & 0xFFF);
      const unsigned wb = (unsigned)(e >> 24);
      const int t = compR[v];
      bool mutual = false;
      const u64 te = minE[t];
      if (te != U64MAX) {
        const int tv = (int)(te & 0xFFF);
        mutual = (compR[tv] == i);
      }
      if (!(mutual && i < t)) {
        const int slot = atomicAdd(&counters[2], 1);
        if (slot < NN) { eu[slot] = u; ev[slot] = v; ew[slot] = wb; }
      }
    }
  }
}

// ---------------------------------------------------------------------------
// block-wide exclusive scan over 4096 LDS ints (1024 threads, 4/thread)
// ---------------------------------------------------------------------------
__device__ __forceinline__ void scan4096(int* arr, int* tmp16, int tid)
{
  __syncthreads();
  const int base = tid * 4;
  const int c0 = arr[base], c1 = arr[base + 1], c2 = arr[base + 2], c3 = arr[base + 3];
  const int lsum = c0 + c1 + c2 + c3;
  const int lane = tid & 63, wid = tid >> 6;
  int incl = lsum;
  #pragma unroll
  for (int o = 1; o < 64; o <<= 1) {
    const int t = __shfl_up(incl, o);
    if (lane >= o) incl += t;
  }
  if (lane == 63) tmp16[wid] = incl;
  __syncthreads();
  if (tid == 0) {
    int run = 0;
    for (int w = 0; w < 16; ++w) { const int t = tmp16[w]; tmp16[w] = run; run += t; }
  }
  __syncthreads();
  const int excl = tmp16[wid] + incl - lsum;
  arr[base]     = excl;
  arr[base + 1] = excl + c0;
  arr[base + 2] = excl + c0 + c1;
  arr[base + 3] = excl + c0 + c1 + c2;
  __syncthreads();
}

// ---------------------------------------------------------------------------
// Kernel 2 (single block): root MST at 0, child lists desc-(wbits,idx)
// (== reversed Prim order), level buckets, carrier-segment list sorted by
// depth-of-last-node DESC (topological order of segments), w_edge, ready=0,
// segment-queue cursor=0.
// ---------------------------------------------------------------------------
__global__ __launch_bounds__(1024) void mrf_root_kernel(
    const float* __restrict__ dist,
    const int* __restrict__ eu, const int* __restrict__ ev, const unsigned* __restrict__ ew,
    int* __restrict__ parent_g, int* __restrict__ childStart, int* __restrict__ childList,
    int* __restrict__ levStart, int* __restrict__ levNodes, int* __restrict__ segList,
    int* __restrict__ meta, float* __restrict__ w_edge,
    u64* __restrict__ adjList, int* __restrict__ ready, int* __restrict__ cursor)
{
  __shared__ int s_deg[NN];
  __shared__ int s_start[NN];
  __shared__ int s_cur[NN];
  __shared__ int s_parent[NN];
  __shared__ unsigned short s_dep[NN];
  __shared__ unsigned short s_fr[2][NN];
  __shared__ int s_tmp16[16];
  __shared__ int s_fcnt, s_nf;

  const int tid = threadIdx.x;

  for (int j = tid; j < NN; j += 1024) ready[j] = 0;   // fresh every call
  if (tid == 0) cursor[0] = 0;

  // ---- adjacency ----
  for (int j = tid; j < NN; j += 1024) s_deg[j] = 0;
  __syncthreads();
  for (int e = tid; e < NN - 1; e += 1024) {
    atomicAdd(&s_deg[eu[e] & (NN - 1)], 1);
    atomicAdd(&s_deg[ev[e] & (NN - 1)], 1);
  }
  __syncthreads();
  for (int j = tid; j < NN; j += 1024) s_start[j] = s_deg[j];
  scan4096(s_start, s_tmp16, tid);
  for (int j = tid; j < NN; j += 1024) s_cur[j] = s_start[j];
  __syncthreads();
  for (int e = tid; e < NN - 1; e += 1024) {
    const int u = eu[e] & (NN - 1), v = ev[e] & (NN - 1);
    const u64 wb = (u64)ew[e];
    const int p1 = atomicAdd(&s_cur[u], 1);
    adjList[p1] = (wb << 12) | (u64)v;
    const int p2 = atomicAdd(&s_cur[v], 1);
    adjList[p2] = (wb << 12) | (u64)u;
  }
  __syncthreads();

  // ---- BFS from node 0 ----
  for (int j = tid; j < NN; j += 1024) { s_parent[j] = 0; s_dep[j] = 0; }
  if (tid == 0) { s_fcnt = 1; s_nf = 0; s_fr[0][0] = 0; }
  __syncthreads();
  int cur = 0, lev = 0;
  while (true) {
    const int fcnt = s_fcnt;
    if (fcnt == 0) break;
    for (int idx = tid; idx < fcnt; idx += 1024) {
      const int x = s_fr[cur][idx];
      const int st = s_start[x], dg = s_deg[x];
      for (int a = 0; a < dg; ++a) {
        const u64 ent = adjList[st + a];
        const int nb = (int)(ent & 0xFFF);
        if (nb != s_parent[x] || x == 0) {
          s_parent[nb] = x;
          s_dep[nb] = (unsigned short)(lev + 1);
          const int slot = atomicAdd(&s_nf, 1);
          s_fr[1 - cur][slot] = (unsigned short)nb;
        }
      }
    }
    __syncthreads();
    if (tid == 0) { s_fcnt = s_nf; s_nf = 0; }
    ++lev;
    cur ^= 1;
    __syncthreads();
  }
  const int numLev = lev;
  if (tid == 0) { s_parent[0] = 0; meta[0] = numLev; }
  __syncthreads();

  // ---- childStart ----
  int* s_cs2 = (int*)s_fr;     // 4096 ints, overlays frontier memory
  for (int j = tid; j < NN; j += 1024) s_cs2[j] = s_deg[j] - (j != 0 ? 1 : 0);
  scan4096(s_cs2, s_tmp16, tid);
  for (int j = tid; j < NN; j += 1024) childStart[j] = s_cs2[j];
  if (tid == 0) childStart[NN] = NN - 1;
  __syncthreads();

  // ---- children sorted descending by (wbits, idx) ----
  for (int p = tid; p < NN; p += 1024) {
    const int st = s_start[p], dg = s_deg[p], cs = s_cs2[p];
    const int par = s_parent[p];
    u64 buf[16];
    int m = 0;
    for (int a = 0; a < dg; ++a) {
      const u64 ent = adjList[st + a];
      const int nb = (int)(ent & 0xFFF);
      if (p != 0 && nb == par) continue;
      if (m < 16) {
        int q = m;
        while (q > 0 && buf[q - 1] < ent) { buf[q] = buf[q - 1]; --q; }
        buf[q] = ent;
        ++m;
      } else {
        childList[cs + m] = nb;
        ++m;
      }
    }
    const int lim = m < 16 ? m : 16;
    for (int k = 0; k < lim; ++k) childList[cs + k] = (int)(buf[k] & 0xFFF);
  }

  // ---- level buckets ----
  for (int j = tid; j < NN; j += 1024) s_cur[j] = 0;
  __syncthreads();
  for (int j = tid; j < NN; j += 1024) atomicAdd(&s_cur[s_dep[j]], 1);
  scan4096(s_cur, s_tmp16, tid);
  for (int j = tid; j < NN; j += 1024) { levStart[j] = s_cur[j]; s_start[j] = s_cur[j]; }
  if (tid == 0) levStart[NN] = NN;
  __syncthreads();
  for (int j = tid; j < NN; j += 1024) {
    const int pos = atomicAdd(&s_start[s_dep[j]], 1);
    levNodes[pos] = j;
  }
  __syncthreads();

  // ---- carrier segments: one per leaf; key = depth of segment's LAST node.
  if (tid == 0) s_nf = 0;
  for (int j = tid; j < NN; j += 1024) s_cur[j] = 0;   // bucket counts
  __syncthreads();
  for (int j = tid; j < NN; j += 1024) {
    const int ce = (j == NN - 1) ? (NN - 1) : s_cs2[j + 1];
    int key = -1;
    if (ce - s_cs2[j] == 0) {          // leaf
      int c = j;
      while (c != 0) {
        const int par = s_parent[c];
        if (childList[s_cs2[par]] != c) break;   // c is not the carrier
        c = par;
      }
      key = s_dep[c];
      atomicAdd(&s_cur[numLev - 1 - key], 1);
      atomicAdd(&s_nf, 1);
    }
    s_deg[j] = key;                    // s_deg reused as per-leaf key store
  }
  scan4096(s_cur, s_tmp16, tid);
  for (int j = tid; j < NN; j += 1024) s_start[j] = s_cur[j];
  __syncthreads();
  for (int j = tid; j < NN; j += 1024) {
    const int key = s_deg[j];
    if (key >= 0) {
      const int pos = atomicAdd(&s_start[numLev - 1 - key], 1);
      segList[pos] = j;
    }
  }
  if (tid == 0) meta[1] = s_nf;

  // ---- outputs ----
  for (int j = tid; j < NN; j += 1024) {
    parent_g[j] = s_parent[j];
    w_edge[j] = (j == 0) ? 0.0f
                         : expf(-dist[(size_t)j * NN + s_parent[j]] / 0.18f);
  }
}

// ---------------------------------------------------------------------------
// Kernel 3 (cooperative, carrier-chain dataflow, 768 threads):
// per-node argmax mapped as (lc-chunk h in [0,8)) x (lp-quartet t in [0,86)):
// one float4 Apad load + one s_b LDS read serve 4 elements. Dynamic
// topological work queue. Chains keep belief in LDS; branch nodes poll;
// non-carrier ends publish via write-through L3 atomics. msgbuf aliases d_out.
// ---------------------------------------------------------------------------
__global__ __launch_bounds__(768) void mrf_solve_kernel(
    const float* __restrict__ unary, const float* __restrict__ Apad,
    float* __restrict__ msgbuf, unsigned short* __restrict__ ptrbuf,
    const int* __restrict__ parent, const int* __restrict__ childStart,
    const int* __restrict__ childList, const int* __restrict__ levStart,
    const int* __restrict__ levNodes, const int* __restrict__ segList,
    const float* __restrict__ w_edge,
    int* __restrict__ labels, const int* __restrict__ meta,
    int* __restrict__ ready, int* __restrict__ cursor)
{
  __shared__ float s_b[APITCH];
  __shared__ float s_pv[8][APITCH];
  __shared__ int   s_pi[8][APITCH];
  __shared__ int   s_lab[NN];
  __shared__ int   s_sidx;
  const int tid = threadIdx.x;
  const bool act = (tid < 688);
  const int t = act ? (tid % 86) : 0;     // lp quartet index
  const int h = act ? (tid / 86) : 0;     // lc chunk index
  const int lc0 = h * 43;
  const int lc1 = (h == 7) ? LBL : (lc0 + 43);

  int numLev = meta[0];
  if (numLev < 1) numLev = 1;
  if (numLev > NN) numLev = NN;
  int numSegs = meta[1];
  if (numSegs < 1) numSegs = 1;
  if (numSegs > NN) numSegs = NN;

  bool didRoot = false;

  while (!didRoot) {
    if (tid == 0) s_sidx = atomicAdd(cursor, 1);   // dynamic topological pop
    __syncthreads();
    const int sidx = s_sidx;
    if (sidx >= numSegs) break;

    int v = segList[sidx] & (NN - 1);
    if (tid < LBL) s_b[tid] = unary[(size_t)v * LBL + tid];   // leaf belief
    __syncthreads();

    while (true) {
      if (v == 0) {
        if (tid == 0) {
          float bv = s_b[0]; int bi = 0;
          for (int l = 1; l < LBL; ++l)
            if (s_b[l] > bv) { bv = s_b[l]; bi = l; }
          labels[0] = bi;
          s_lab[0] = bi;
        }
        __syncthreads();
        didRoot = true;
        break;
      }

      // ---- partial argmax: chunk h of lc, quartet t of lp ----
      if (act) {
        const float w = w_edge[v];
        const float4* __restrict__ Ap4 = (const float4*)Apad;  // row = 86 float4
        float4 a = Ap4[(size_t)lc0 * 86 + t];
        float sb = s_b[lc0];
        float bv0 = __fadd_rn(sb, __fmul_rn(w, a.x));
        float bv1 = __fadd_rn(sb, __fmul_rn(w, a.y));
        float bv2 = __fadd_rn(sb, __fmul_rn(w, a.z));
        float bv3 = __fadd_rn(sb, __fmul_rn(w, a.w));
        int bi0 = lc0, bi1 = lc0, bi2 = lc0, bi3 = lc0;
        #pragma unroll 2
        for (int lc = lc0 + 1; lc < lc1; ++lc) {
          const float4 av = Ap4[(size_t)lc * 86 + t];
          const float sbl = s_b[lc];
          const float s0 = __fadd_rn(sbl, __fmul_rn(w, av.x));
          const float s1 = __fadd_rn(sbl, __fmul_rn(w, av.y));
          const float s2 = __fadd_rn(sbl, __fmul_rn(w, av.z));
          const float s3 = __fadd_rn(sbl, __fmul_rn(w, av.w));
          if (s0 > bv0) { bv0 = s0; bi0 = lc; }
          if (s1 > bv1) { bv1 = s1; bi1 = lc; }
          if (s2 > bv2) { bv2 = s2; bi2 = lc; }
          if (s3 > bv3) { bv3 = s3; bi3 = lc; }
        }
        const int lpb = t * 4;
        s_pv[h][lpb + 0] = bv0; s_pi[h][lpb + 0] = bi0;
        s_pv[h][lpb + 1] = bv1; s_pi[h][lpb + 1] = bi1;
        s_pv[h][lpb + 2] = bv2; s_pi[h][lpb + 2] = bi2;
        s_pv[h][lpb + 3] = bv3; s_pi[h][lpb + 3] = bi3;
      }
      __syncthreads();

      // ---- combine chunks (ascending h == ascending lc; strict >) ----
      float fbv = 0.0f;
      if (tid < LBL) {
        fbv = s_pv[0][tid];
        int fbi = s_pi[0][tid];
        #pragma unroll
        for (int hh = 1; hh < 8; ++hh) {
          const float pv = s_pv[hh][tid];
          if (pv > fbv) { fbv = pv; fbi = s_pi[hh][tid]; }
        }
        s_pi[0][tid] = fbi;   // own column only: no cross-thread hazard
      }
      __syncthreads();

      // ---- ptr store as aligned u32 pairs ----
      if (tid < 172) {
        const unsigned lo = (unsigned)s_pi[0][2 * tid] & 0xFFFFu;
        const unsigned hi = (2 * tid + 1 < LBL)
                              ? ((unsigned)s_pi[0][2 * tid + 1] & 0xFFFFu) : 0u;
        __hip_atomic_store((unsigned*)(ptrbuf + (size_t)v * PSTRIDE + 2 * tid),
                           lo | (hi << 16),
                           __ATOMIC_RELAXED, __HIP_MEMORY_SCOPE_AGENT);
      }

      const int p = parent[v] & (NN - 1);
      const int csp = childStart[p];
      int degp = childStart[p + 1] - csp;
      if (degp < 1) degp = 1;
      if (degp > 64) degp = 64;
      const bool isCarrier = ((childList[csp] & (NN - 1)) == v);

      if (!isCarrier) {
        // segment ends: publish msg via write-through, then release count
        if (tid < LBL)
          __hip_atomic_store((unsigned*)&msgbuf[(size_t)v * LBL + tid],
                             __float_as_uint(fbv),
                             __ATOMIC_RELAXED, __HIP_MEMORY_SCOPE_AGENT);
        __syncthreads();
        if (tid == 0)
          __hip_atomic_fetch_add(&ready[p], 1,
                                 __ATOMIC_RELEASE, __HIP_MEMORY_SCOPE_AGENT);
        break;
      }

      // carrier: wait only for the OTHER children (if any), then fuse locally
      if (degp > 1 && tid == 0) {
        long long guard = 0;
        while (__hip_atomic_load(&ready[p], __ATOMIC_RELAXED,
                                 __HIP_MEMORY_SCOPE_AGENT) < degp - 1) {
          __builtin_amdgcn_s_sleep(1);
          if (++guard > 30000000LL) break;   // anti-hang escape (never expected)
        }
      }
      __syncthreads();

      if (tid < LBL) {
        float nb = __fadd_rn(unary[(size_t)p * LBL + tid], fbv);  // carrier first
        for (int k = 1; k < degp; ++k) {
          const int ch = childList[csp + k] & (NN - 1);
          const unsigned um = __hip_atomic_load(
              (const unsigned*)&msgbuf[(size_t)ch * LBL + tid],
              __ATOMIC_RELAXED, __HIP_MEMORY_SCOPE_AGENT);
          nb = __fadd_rn(nb, __uint_as_float(um));
        }
        s_b[tid] = nb;
      }
      v = p;
      __syncthreads();   // s_b update visible before next iteration reads
    }
  }

  // -------- downward backtracking (the block that finished the root) --------
  if (!didRoot) return;
  __syncthreads();
  for (int lev = 1; lev < numLev; ++lev) {
    int ls = levStart[lev], le = levStart[lev + 1];
    if (ls < 0) ls = 0;
    if (le > NN) le = NN;
    for (int idx = ls + tid; idx < le; idx += 768) {
      const int c = levNodes[idx] & (NN - 1);
      int pl = s_lab[parent[c] & (NN - 1)];
      if (pl < 0) pl = 0;
      if (pl >= LBL) pl = LBL - 1;
      const unsigned pk = __hip_atomic_load(
          (const unsigned*)(ptrbuf + (size_t)c * PSTRIDE + (pl & ~1)),
          __ATOMIC_RELAXED, __HIP_MEMORY_SCOPE_AGENT);
      const int lab = (pl & 1) ? (int)(pk >> 16) : (int)(pk & 0xFFFFu);
      s_lab[c] = lab;
      labels[c] = lab;
    }
    __syncthreads();
  }
}

// ---------------------------------------------------------------------------
// Kernel 4: output fill (2*onehot - 1) * 1e5 (overwrites all of d_out)
// ---------------------------------------------------------------------------
__global__ void mrf_out_kernel(const int* __restrict__ labels, float* __restrict__ out)
{
  const int id = blockIdx.x * blockDim.x + threadIdx.x;
  if (id >= NN * LBL) return;
  const int c = id / LBL;
  const int l = id - c * LBL;
  out[id] = (l == labels[c]) ? 100000.0f : -100000.0f;
}

extern "C" void kernel_launch(void* const* d_in, const int* in_sizes, int n_in,
                              void* d_out, int out_size, void* d_ws, size_t ws_size,
                              hipStream_t stream)
{
  (void)in_sizes; (void)n_in; (void)out_size; (void)ws_size;
  const float* unary = (const float*)d_in[0];
  const float* dist  = (const float*)d_in[1];
  const float* A     = (const float*)d_in[2];
  float* out = (float*)d_out;

  char* ws = (char*)d_ws;
  size_t off = 0;
  auto take = [&](size_t bytes) -> void* {
    void* p = (void*)(ws + off);
    off += (bytes + 255) & ~(size_t)255;
    return p;
  };
  float* msgbuf = out;   // aliases d_out; fully overwritten by mrf_out_kernel
  unsigned short* ptrbuf = (unsigned short*)take((size_t)NN * PSTRIDE * sizeof(unsigned short));
  float*    Apad       = (float*)   take((size_t)LBL * APITCH * sizeof(float));
  u64*      cand       = (u64*)     take((size_t)NN * CANDCAP * sizeof(u64));
  int*      candCnt    = (int*)     take(NN * sizeof(int));
  int*      compA      = (int*)     take(NN * sizeof(int));
  int*      compB      = (int*)     take(NN * sizeof(int));
  u64*      minEa      = (u64*)     take(NN * sizeof(u64));
  u64*      minEb      = (u64*)     take(NN * sizeof(u64));
  int*      eu         = (int*)     take(NN * sizeof(int));
  int*      ev         = (int*)     take(NN * sizeof(int));
  unsigned* ew         = (unsigned*)take(NN * sizeof(unsigned));
  int*      counters   = (int*)     take(256);
  int*      parent     = (int*)     take(NN * sizeof(int));
  int*      childStart = (int*)     take((NN + 1) * sizeof(int));
  int*      childList  = (int*)     take(NN * sizeof(int));
  int*      levStart   = (int*)     take((NN + 1) * sizeof(int));
  int*      levNodes   = (int*)     take(NN * sizeof(int));
  int*      segList    = (int*)     take(NN * sizeof(int));
  int*      labels     = (int*)     take(NN * sizeof(int));
  int*      meta       = (int*)     take(256);
  float*    w_edge     = (float*)   take(NN * sizeof(float));
  int*      ready      = (int*)     take(NN * sizeof(int));
  int*      cursor     = (int*)     take(256);
  u64*      adjList    = (u64*)     take((size_t)2 * NN * sizeof(u64));

  hipLaunchKernelGGL(mrf_init_kernel, dim3((LBL * APITCH + 255) / 256), dim3(256),
                     0, stream, A, Apad, compA, minEa, minEb, counters);

  // round 0: full scan + candidate shortlist build
  hipLaunchKernelGGL(mrf_scan0_kernel, dim3(256), dim3(1024), 0, stream,
                     dist, compA, minEa, counters, cand, candCnt);
  hipLaunchKernelGGL(mrf_hook_kernel, dim3(4), dim3(1024), 0, stream,
                     compA, compB, minEa, minEb, eu, ev, ew, counters, 0);

  for (int r = 1; r < MST_ROUNDS; ++r) {
    const int* compR = (r & 1) ? compB : compA;
    int*       compW = (r & 1) ? compA : compB;
    u64*       mcur  = (r & 1) ? minEb : minEa;
    u64*       mnext = (r & 1) ? minEa : minEb;
    hipLaunchKernelGGL(mrf_scanc_kernel, dim3(16), dim3(256), 0, stream,
                       dist, compR, mcur, counters, r, cand, candCnt);
    hipLaunchKernelGGL(mrf_hook_kernel, dim3(4), dim3(1024), 0, stream,
                       compR, compW, mcur, mnext, eu, ev, ew, counters, r);
  }

  hipLaunchKernelGGL(mrf_root_kernel, dim3(1), dim3(1024), 0, stream,
                     dist, eu, ev, ew, parent, childStart, childList,
                     levStart, levNodes, segList, meta, w_edge, adjList,
                     ready, cursor);

  {
    void* args[] = {
      (void*)&unary, (void*)&Apad, (void*)&msgbuf, (void*)&ptrbuf,
      (void*)&parent, (void*)&childStart, (void*)&childList,
      (void*)&levStart, (void*)&levNodes, (void*)&segList, (void*)&w_edge,
      (void*)&labels, (void*)&meta, (void*)&ready, (void*)&cursor
    };
    hipLaunchCooperativeKernel((void*)mrf_solve_kernel, dim3(256), dim3(768),
                               args, 0, stream);
  }

  const int total = NN * LBL;
  hipLaunchKernelGGL(mrf_out_kernel, dim3((total + 255) / 256), dim3(256), 0, stream,
                     labels, out);
}

// Round 15
// 906.622 us; speedup vs baseline: 1.1839x; 1.1839x over previous
//
#include <hip/hip_runtime.h>
#include <hip/hip_cooperative_groups.h>
#include <math.h>

namespace cg = cooperative_groups;
typedef unsigned long long u64;

#define NN 4096
#define LBL 343
#define PSTRIDE 344   // ptrbuf row stride (u16), even => aligned u32 pair stores
#define APITCH 344    // padded A row stride (floats); 344*4B = 1376 ≡ 0 mod 16
#define U64MAX 0xFFFFFFFFFFFFFFFFull
#define MST_ROUNDS 12 // components at least halve per round: 2^12 = 4096

// ---------------------------------------------------------------------------
// Init: identity components, minE parity buffers, counters, Apad build.
// ---------------------------------------------------------------------------
__global__ void mrf_init_kernel(const float* __restrict__ A, float* __restrict__ Apad,
                                int* __restrict__ compA,
                                u64* __restrict__ minEa, u64* __restrict__ minEb,
                                int* __restrict__ counters)
{
  const int id = blockIdx.x * 256 + threadIdx.x;
  if (id < NN) { compA[id] = id; minEa[id] = U64MAX; minEb[id] = U64MAX; }
  if (id == 0) { counters[0] = NN; counters[1] = NN; counters[2] = 0; }
  if (id < LBL * APITCH) {
    const int r = id / APITCH;
    const int c = id - r * APITCH;
    Apad[id] = (c < LBL) ? A[r * LBL + c] : 0.0f;
  }
}

// ---------------------------------------------------------------------------
// Boruvka phase 1: per-row min outgoing edge, one wave per row, LDS dedupe.
// ---------------------------------------------------------------------------
__global__ __launch_bounds__(1024) void mrf_scan_kernel(
    const float* __restrict__ dist, const int* __restrict__ compR,
    u64* __restrict__ minE, int* __restrict__ counters, int round)
{
  __shared__ int s_cc[16];
  __shared__ u64 s_cv[16];

  if (blockIdx.x == 0 && threadIdx.x == 0) counters[round & 1] = 0;
  if (round > 0 && counters[(round - 1) & 1] <= 1) return;

  const int i    = (blockIdx.x * 1024 + threadIdx.x) >> 6;  // row 0..4095
  const int lane = threadIdx.x & 63;
  const int wib  = threadIdx.x >> 6;

  const int ci = compR[i];
  const float4* rowp = (const float4*)(dist + (size_t)i * NN);
  const int4* cp = (const int4*)compR;
  u64 best = U64MAX;
  #pragma unroll 4
  for (int k = 0; k < 16; ++k) {
    const int q = k * 64 + lane;
    const float4 dv = rowp[q];
    const int4 cv = cp[q];
    const int j0 = q * 4;
    if (cv.x != ci) { const u64 p = ((u64)__float_as_uint(dv.x) << 24) | ((u64)i << 12) | (u64)(j0    ); best = best < p ? best : p; }
    if (cv.y != ci) { const u64 p = ((u64)__float_as_uint(dv.y) << 24) | ((u64)i << 12) | (u64)(j0 + 1); best = best < p ? best : p; }
    if (cv.z != ci) { const u64 p = ((u64)__float_as_uint(dv.z) << 24) | ((u64)i << 12) | (u64)(j0 + 2); best = best < p ? best : p; }
    if (cv.w != ci) { const u64 p = ((u64)__float_as_uint(dv.w) << 24) | ((u64)i << 12) | (u64)(j0 + 3); best = best < p ? best : p; }
  }
  #pragma unroll
  for (int sh = 32; sh >= 1; sh >>= 1) {
    const u64 o = __shfl_down(best, sh);
    best = best < o ? best : o;
  }
  if (lane == 0) {
    s_cc[wib] = (best == U64MAX) ? -1 : ci;
    s_cv[wib] = best;
  }
  __syncthreads();
  if (threadIdx.x == 0) {
    for (int a = 0; a < 16; ++a) {
      const int c = s_cc[a];
      if (c < 0) continue;
      bool dup = false;
      for (int b2 = 0; b2 < a; ++b2) if (s_cc[b2] == c) { dup = true; break; }
      if (dup) continue;
      u64 b = s_cv[a];
      for (int b2 = a + 1; b2 < 16; ++b2)
        if (s_cc[b2] == c && s_cv[b2] < b) b = s_cv[b2];
      atomicMin(&minE[c & (NN - 1)], b);
    }
  }
}

// ---------------------------------------------------------------------------
// Boruvka phases 2+3 fused (unchanged, passing).
// ---------------------------------------------------------------------------
__global__ __launch_bounds__(1024) void mrf_hook_kernel(
    const int* __restrict__ compR, int* __restrict__ compW,
    const u64* __restrict__ minE, u64* __restrict__ minEnext,
    int* __restrict__ eu, int* __restrict__ ev, unsigned* __restrict__ ew,
    int* __restrict__ counters, int round)
{
  if (round > 0 && counters[(round - 1) & 1] <= 1) return;
  const int i = blockIdx.x * 1024 + threadIdx.x;
  if (i >= NN) return;
  minEnext[i] = U64MAX;

  const int r0 = compR[i];
  int cur = r0;
  for (int guard = 0; guard < NN + 2; ++guard) {
    const u64 e = minE[cur];
    if (e == U64MAX) break;
    const int v = (int)(e & 0xFFF);
    const int t = compR[v];
    if (t == cur) break;
    const u64 te = minE[t];
    if (te != U64MAX) {
      const int tv = (int)(te & 0xFFF);
      if (compR[tv] == cur && cur < t) break;    // mutual pair: cur wins
    }
    cur = t;
  }
  compW[i] = cur;
  if (cur == i) atomicAdd(&counters[round & 1], 1);

  if (r0 == i) {
    const u64 e = minE[i];
    if (e != U64MAX) {
      const int v = (int)(e & 0xFFF);
      const int u = (int)((e >> 12) & 0xFFF);
      const unsigned wb = (unsigned)(e >> 24);
      const int t = compR[v];
      bool mutual = false;
      const u64 te = minE[t];
      if (te != U64MAX) {
        const int tv = (int)(te & 0xFFF);
        mutual = (compR[tv] == i);
      }
      if (!(mutual && i < t)) {
        const int slot = atomicAdd(&counters[2], 1);
        if (slot < NN) { eu[slot] = u; ev[slot] = v; ew[slot] = wb; }
      }
    }
  }
}

// ---------------------------------------------------------------------------
// block-wide exclusive scan over 4096 LDS ints (1024 threads, 4/thread)
// ---------------------------------------------------------------------------
__device__ __forceinline__ void scan4096(int* arr, int* tmp16, int tid)
{
  __syncthreads();
  const int base = tid * 4;
  const int c0 = arr[base], c1 = arr[base + 1], c2 = arr[base + 2], c3 = arr[base + 3];
  const int lsum = c0 + c1 + c2 + c3;
  const int lane = tid & 63, wid = tid >> 6;
  int incl = lsum;
  #pragma unroll
  for (int o = 1; o < 64; o <<= 1) {
    const int t = __shfl_up(incl, o);
    if (lane >= o) incl += t;
  }
  if (lane == 63) tmp16[wid] = incl;
  __syncthreads();
  if (tid == 0) {
    int run = 0;
    for (int w = 0; w < 16; ++w) { const int t = tmp16[w]; tmp16[w] = run; run += t; }
  }
  __syncthreads();
  const int excl = tmp16[wid] + incl - lsum;
  arr[base]     = excl;
  arr[base + 1] = excl + c0;
  arr[base + 2] = excl + c0 + c1;
  arr[base + 3] = excl + c0 + c1 + c2;
  __syncthreads();
}

// ---------------------------------------------------------------------------
// Kernel 2 (single block): root MST at 0. Adjacency lives entirely in LDS
// (s_adj, 64KB; total static LDS ~156KB of the CU's 160KB — single-block
// kernel, occupancy irrelevant). BFS runs on WAVE 0 ONLY, wave-synchronous:
// no block barriers per level; cross-lane LDS visibility enforced with
// s_waitcnt lgkmcnt(0) + sched_barrier(0) at the two consume points.
// Then child lists desc-(wbits,idx) (== reversed Prim order), level buckets,
// carrier-segment list (topological order), w_edge, ready=0, cursor=0.
// ---------------------------------------------------------------------------
__global__ __launch_bounds__(1024) void mrf_root_kernel(
    const float* __restrict__ dist,
    const int* __restrict__ eu, const int* __restrict__ ev, const unsigned* __restrict__ ew,
    int* __restrict__ parent_g, int* __restrict__ childStart, int* __restrict__ childList,
    int* __restrict__ levStart, int* __restrict__ levNodes, int* __restrict__ segList,
    int* __restrict__ meta, float* __restrict__ w_edge,
    int* __restrict__ ready, int* __restrict__ cursor)
{
  __shared__ int s_deg[NN];                 // 16 KB
  __shared__ int s_start[NN];               // 16 KB
  __shared__ int s_cur[NN];                 // 16 KB
  __shared__ int s_parent[NN];              // 16 KB
  __shared__ unsigned short s_dep[NN];      // 8 KB
  __shared__ unsigned short s_fr[2][NN];    // 16 KB (reused as ints later)
  __shared__ u64 s_adj[2 * (NN - 1)];       // 64 KB (8190 entries)
  __shared__ int s_tmp16[16];
  __shared__ int s_fcnt, s_nf;

  const int tid = threadIdx.x;

  for (int j = tid; j < NN; j += 1024) ready[j] = 0;   // fresh every call
  if (tid == 0) cursor[0] = 0;

  // ---- adjacency (into LDS) ----
  for (int j = tid; j < NN; j += 1024) s_deg[j] = 0;
  __syncthreads();
  for (int e = tid; e < NN - 1; e += 1024) {
    atomicAdd(&s_deg[eu[e] & (NN - 1)], 1);
    atomicAdd(&s_deg[ev[e] & (NN - 1)], 1);
  }
  __syncthreads();
  for (int j = tid; j < NN; j += 1024) s_start[j] = s_deg[j];
  scan4096(s_start, s_tmp16, tid);
  for (int j = tid; j < NN; j += 1024) s_cur[j] = s_start[j];
  __syncthreads();
  for (int e = tid; e < NN - 1; e += 1024) {
    const int u = eu[e] & (NN - 1), v = ev[e] & (NN - 1);
    const u64 wb = (u64)ew[e];
    const int p1 = atomicAdd(&s_cur[u], 1);
    s_adj[p1 & (2 * NN - 1)] = (wb << 12) | (u64)v;
    const int p2 = atomicAdd(&s_cur[v], 1);
    s_adj[p2 & (2 * NN - 1)] = (wb << 12) | (u64)u;
  }
  // ---- BFS init ----
  for (int j = tid; j < NN; j += 1024) { s_parent[j] = 0; s_dep[j] = 0; }
  if (tid == 0) { s_fcnt = 1; s_nf = 0; s_fr[0][0] = 0; }
  __syncthreads();

  // ---- BFS from node 0: WAVE 0 ONLY, wave-synchronous ----
  if (tid < 64) {
    int cur = 0, lev = 0;
    while (true) {
      asm volatile("s_waitcnt lgkmcnt(0)" ::: "memory");
      __builtin_amdgcn_sched_barrier(0);
      const int fcnt = s_fcnt;
      if (fcnt == 0) break;
      for (int idx = tid; idx < fcnt; idx += 64) {
        const int x = s_fr[cur][idx];
        const int st = s_start[x], dg = s_deg[x];
        for (int a = 0; a < dg; ++a) {
          const u64 ent = s_adj[(st + a) & (2 * NN - 1)];
          const int nb = (int)(ent & 0xFFF);
          if (nb != s_parent[x] || x == 0) {     // tree: each nb found once
            s_parent[nb] = x;
            s_dep[nb] = (unsigned short)(lev + 1);
            const int slot = atomicAdd(&s_nf, 1);
            s_fr[1 - cur][slot] = (unsigned short)nb;
          }
        }
      }
      asm volatile("s_waitcnt lgkmcnt(0)" ::: "memory");
      __builtin_amdgcn_sched_barrier(0);
      if (tid == 0) { s_fcnt = s_nf; s_nf = 0; }
      ++lev;
      cur ^= 1;
    }
    if (tid == 0) s_fcnt = lev;                  // stash numLev
  }
  __syncthreads();
  const int numLev = s_fcnt;
  if (tid == 0) { s_parent[0] = 0; meta[0] = numLev; }
  __syncthreads();

  // ---- childStart ----
  int* s_cs2 = (int*)s_fr;     // 4096 ints, overlays frontier memory
  for (int j = tid; j < NN; j += 1024) s_cs2[j] = s_deg[j] - (j != 0 ? 1 : 0);
  scan4096(s_cs2, s_tmp16, tid);
  for (int j = tid; j < NN; j += 1024) childStart[j] = s_cs2[j];
  if (tid == 0) childStart[NN] = NN - 1;
  __syncthreads();

  // ---- children sorted descending by (wbits, idx) ----
  for (int p = tid; p < NN; p += 1024) {
    const int st = s_start[p], dg = s_deg[p], cs = s_cs2[p];
    const int par = s_parent[p];
    u64 buf[16];
    int m = 0;
    for (int a = 0; a < dg; ++a) {
      const u64 ent = s_adj[(st + a) & (2 * NN - 1)];
      const int nb = (int)(ent & 0xFFF);
      if (p != 0 && nb == par) continue;
      if (m < 16) {
        int q = m;
        while (q > 0 && buf[q - 1] < ent) { buf[q] = buf[q - 1]; --q; }
        buf[q] = ent;
        ++m;
      } else {
        childList[cs + m] = nb;
        ++m;
      }
    }
    const int lim = m < 16 ? m : 16;
    for (int k = 0; k < lim; ++k) childList[cs + k] = (int)(buf[k] & 0xFFF);
  }

  // ---- level buckets ----
  for (int j = tid; j < NN; j += 1024) s_cur[j] = 0;
  __syncthreads();
  for (int j = tid; j < NN; j += 1024) atomicAdd(&s_cur[s_dep[j]], 1);
  scan4096(s_cur, s_tmp16, tid);
  for (int j = tid; j < NN; j += 1024) { levStart[j] = s_cur[j]; s_start[j] = s_cur[j]; }
  if (tid == 0) levStart[NN] = NN;
  __syncthreads();
  for (int j = tid; j < NN; j += 1024) {
    const int pos = atomicAdd(&s_start[s_dep[j]], 1);
    levNodes[pos] = j;
  }
  __syncthreads();

  // ---- carrier segments: one per leaf; key = depth of segment's LAST node.
  if (tid == 0) s_nf = 0;
  for (int j = tid; j < NN; j += 1024) s_cur[j] = 0;   // bucket counts
  __syncthreads();
  for (int j = tid; j < NN; j += 1024) {
    const int ce = (j == NN - 1) ? (NN - 1) : s_cs2[j + 1];
    int key = -1;
    if (ce - s_cs2[j] == 0) {          // leaf
      int c = j;
      while (c != 0) {
        const int par = s_parent[c];
        if (childList[s_cs2[par]] != c) break;   // c is not the carrier
        c = par;
      }
      key = s_dep[c];
      atomicAdd(&s_cur[numLev - 1 - key], 1);
      atomicAdd(&s_nf, 1);
    }
    s_deg[j] = key;                    // s_deg reused as per-leaf key store
  }
  scan4096(s_cur, s_tmp16, tid);
  for (int j = tid; j < NN; j += 1024) s_start[j] = s_cur[j];
  __syncthreads();
  for (int j = tid; j < NN; j += 1024) {
    const int key = s_deg[j];
    if (key >= 0) {
      const int pos = atomicAdd(&s_start[numLev - 1 - key], 1);
      segList[pos] = j;
    }
  }
  if (tid == 0) meta[1] = s_nf;

  // ---- outputs ----
  for (int j = tid; j < NN; j += 1024) {
    parent_g[j] = s_parent[j];
    w_edge[j] = (j == 0) ? 0.0f
                         : expf(-dist[(size_t)j * NN + s_parent[j]] / 0.18f);
  }
}

// ---------------------------------------------------------------------------
// Kernel 3 (cooperative, carrier-chain dataflow, 768 threads):
// per-node argmax mapped as (lc-chunk h in [0,8)) x (lp-quartet t in [0,86)):
// one float4 Apad load + one s_b LDS read serve 4 elements. Dynamic
// topological work queue. Chains keep belief in LDS; branch nodes poll;
// non-carrier ends publish via write-through L3 atomics. msgbuf aliases d_out.
// ---------------------------------------------------------------------------
__global__ __launch_bounds__(768) void mrf_solve_kernel(
    const float* __restrict__ unary, const float* __restrict__ Apad,
    float* __restrict__ msgbuf, unsigned short* __restrict__ ptrbuf,
    const int* __restrict__ parent, const int* __restrict__ childStart,
    const int* __restrict__ childList, const int* __restrict__ levStart,
    const int* __restrict__ levNodes, const int* __restrict__ segList,
    const float* __restrict__ w_edge,
    int* __restrict__ labels, const int* __restrict__ meta,
    int* __restrict__ ready, int* __restrict__ cursor)
{
  __shared__ float s_b[APITCH];
  __shared__ float s_pv[8][APITCH];
  __shared__ int   s_pi[8][APITCH];
  __shared__ int   s_lab[NN];
  __shared__ int   s_sidx;
  const int tid = threadIdx.x;
  const bool act = (tid < 688);
  const int t = act ? (tid % 86) : 0;     // lp quartet index
  const int h = act ? (tid / 86) : 0;     // lc chunk index
  const int lc0 = h * 43;
  const int lc1 = (h == 7) ? LBL : (lc0 + 43);

  int numLev = meta[0];
  if (numLev < 1) numLev = 1;
  if (numLev > NN) numLev = NN;
  int numSegs = meta[1];
  if (numSegs < 1) numSegs = 1;
  if (numSegs > NN) numSegs = NN;

  bool didRoot = false;

  while (!didRoot) {
    if (tid == 0) s_sidx = atomicAdd(cursor, 1);   // dynamic topological pop
    __syncthreads();
    const int sidx = s_sidx;
    if (sidx >= numSegs) break;

    int v = segList[sidx] & (NN - 1);
    if (tid < LBL) s_b[tid] = unary[(size_t)v * LBL + tid];   // leaf belief
    __syncthreads();

    while (true) {
      if (v == 0) {
        if (tid == 0) {
          float bv = s_b[0]; int bi = 0;
          for (int l = 1; l < LBL; ++l)
            if (s_b[l] > bv) { bv = s_b[l]; bi = l; }
          labels[0] = bi;
          s_lab[0] = bi;
        }
        __syncthreads();
        didRoot = true;
        break;
      }

      // ---- partial argmax: chunk h of lc, quartet t of lp ----
      if (act) {
        const float w = w_edge[v];
        const float4* __restrict__ Ap4 = (const float4*)Apad;  // row = 86 float4
        float4 a = Ap4[(size_t)lc0 * 86 + t];
        float sb = s_b[lc0];
        float bv0 = __fadd_rn(sb, __fmul_rn(w, a.x));
        float bv1 = __fadd_rn(sb, __fmul_rn(w, a.y));
        float bv2 = __fadd_rn(sb, __fmul_rn(w, a.z));
        float bv3 = __fadd_rn(sb, __fmul_rn(w, a.w));
        int bi0 = lc0, bi1 = lc0, bi2 = lc0, bi3 = lc0;
        #pragma unroll 2
        for (int lc = lc0 + 1; lc < lc1; ++lc) {
          const float4 av = Ap4[(size_t)lc * 86 + t];
          const float sbl = s_b[lc];
          const float s0 = __fadd_rn(sbl, __fmul_rn(w, av.x));
          const float s1 = __fadd_rn(sbl, __fmul_rn(w, av.y));
          const float s2 = __fadd_rn(sbl, __fmul_rn(w, av.z));
          const float s3 = __fadd_rn(sbl, __fmul_rn(w, av.w));
          if (s0 > bv0) { bv0 = s0; bi0 = lc; }
          if (s1 > bv1) { bv1 = s1; bi1 = lc; }
          if (s2 > bv2) { bv2 = s2; bi2 = lc; }
          if (s3 > bv3) { bv3 = s3; bi3 = lc; }
        }
        const int lpb = t * 4;
        s_pv[h][lpb + 0] = bv0; s_pi[h][lpb + 0] = bi0;
        s_pv[h][lpb + 1] = bv1; s_pi[h][lpb + 1] = bi1;
        s_pv[h][lpb + 2] = bv2; s_pi[h][lpb + 2] = bi2;
        s_pv[h][lpb + 3] = bv3; s_pi[h][lpb + 3] = bi3;
      }
      __syncthreads();

      // ---- combine chunks (ascending h == ascending lc; strict >) ----
      float fbv = 0.0f;
      if (tid < LBL) {
        fbv = s_pv[0][tid];
        int fbi = s_pi[0][tid];
        #pragma unroll
        for (int hh = 1; hh < 8; ++hh) {
          const float pv = s_pv[hh][tid];
          if (pv > fbv) { fbv = pv; fbi = s_pi[hh][tid]; }
        }
        s_pi[0][tid] = fbi;   // own column only: no cross-thread hazard
      }
      __syncthreads();

      // ---- ptr store as aligned u32 pairs ----
      if (tid < 172) {
        const unsigned lo = (unsigned)s_pi[0][2 * tid] & 0xFFFFu;
        const unsigned hi = (2 * tid + 1 < LBL)
                              ? ((unsigned)s_pi[0][2 * tid + 1] & 0xFFFFu) : 0u;
        __hip_atomic_store((unsigned*)(ptrbuf + (size_t)v * PSTRIDE + 2 * tid),
                           lo | (hi << 16),
                           __ATOMIC_RELAXED, __HIP_MEMORY_SCOPE_AGENT);
      }

      const int p = parent[v] & (NN - 1);
      const int csp = childStart[p];
      int degp = childStart[p + 1] - csp;
      if (degp < 1) degp = 1;
      if (degp > 64) degp = 64;
      const bool isCarrier = ((childList[csp] & (NN - 1)) == v);

      if (!isCarrier) {
        // segment ends: publish msg via write-through, then release count
        if (tid < LBL)
          __hip_atomic_store((unsigned*)&msgbuf[(size_t)v * LBL + tid],
                             __float_as_uint(fbv),
                             __ATOMIC_RELAXED, __HIP_MEMORY_SCOPE_AGENT);
        __syncthreads();
        if (tid == 0)
          __hip_atomic_fetch_add(&ready[p], 1,
                                 __ATOMIC_RELEASE, __HIP_MEMORY_SCOPE_AGENT);
        break;
      }

      // carrier: wait only for the OTHER children (if any), then fuse locally
      if (degp > 1 && tid == 0) {
        long long guard = 0;
        while (__hip_atomic_load(&ready[p], __ATOMIC_RELAXED,
                                 __HIP_MEMORY_SCOPE_AGENT) < degp - 1) {
          __builtin_amdgcn_s_sleep(1);
          if (++guard > 30000000LL) break;   // anti-hang escape (never expected)
        }
      }
      __syncthreads();

      if (tid < LBL) {
        float nb = __fadd_rn(unary[(size_t)p * LBL + tid], fbv);  // carrier first
        for (int k = 1; k < degp; ++k) {
          const int ch = childList[csp + k] & (NN - 1);
          const unsigned um = __hip_atomic_load(
              (const unsigned*)&msgbuf[(size_t)ch * LBL + tid],
              __ATOMIC_RELAXED, __HIP_MEMORY_SCOPE_AGENT);
          nb = __fadd_rn(nb, __uint_as_float(um));
        }
        s_b[tid] = nb;
      }
      v = p;
      __syncthreads();   // s_b update visible before next iteration reads
    }
  }

  // -------- downward backtracking (the block that finished the root) --------
  if (!didRoot) return;
  __syncthreads();
  for (int lev = 1; lev < numLev; ++lev) {
    int ls = levStart[lev], le = levStart[lev + 1];
    if (ls < 0) ls = 0;
    if (le > NN) le = NN;
    for (int idx = ls + tid; idx < le; idx += 768) {
      const int c = levNodes[idx] & (NN - 1);
      int pl = s_lab[parent[c] & (NN - 1)];
      if (pl < 0) pl = 0;
      if (pl >= LBL) pl = LBL - 1;
      const unsigned pk = __hip_atomic_load(
          (const unsigned*)(ptrbuf + (size_t)c * PSTRIDE + (pl & ~1)),
          __ATOMIC_RELAXED, __HIP_MEMORY_SCOPE_AGENT);
      const int lab = (pl & 1) ? (int)(pk >> 16) : (int)(pk & 0xFFFFu);
      s_lab[c] = lab;
      labels[c] = lab;
    }
    __syncthreads();
  }
}

// ---------------------------------------------------------------------------
// Kernel 4: output fill (2*onehot - 1) * 1e5 (overwrites all of d_out)
// ---------------------------------------------------------------------------
__global__ void mrf_out_kernel(const int* __restrict__ labels, float* __restrict__ out)
{
  const int id = blockIdx.x * blockDim.x + threadIdx.x;
  if (id >= NN * LBL) return;
  const int c = id / LBL;
  const int l = id - c * LBL;
  out[id] = (l == labels[c]) ? 100000.0f : -100000.0f;
}

extern "C" void kernel_launch(void* const* d_in, const int* in_sizes, int n_in,
                              void* d_out, int out_size, void* d_ws, size_t ws_size,
                              hipStream_t stream)
{
  (void)in_sizes; (void)n_in; (void)out_size; (void)ws_size;
  const float* unary = (const float*)d_in[0];
  const float* dist  = (const float*)d_in[1];
  const float* A     = (const float*)d_in[2];
  float* out = (float*)d_out;

  char* ws = (char*)d_ws;
  size_t off = 0;
  auto take = [&](size_t bytes) -> void* {
    void* p = (void*)(ws + off);
    off += (bytes + 255) & ~(size_t)255;
    return p;
  };
  float* msgbuf = out;   // aliases d_out; fully overwritten by mrf_out_kernel
  unsigned short* ptrbuf = (unsigned short*)take((size_t)NN * PSTRIDE * sizeof(unsigned short));
  float*    Apad       = (float*)   take((size_t)LBL * APITCH * sizeof(float));
  int*      compA      = (int*)     take(NN * sizeof(int));
  int*      compB      = (int*)     take(NN * sizeof(int));
  u64*      minEa      = (u64*)     take(NN * sizeof(u64));
  u64*      minEb      = (u64*)     take(NN * sizeof(u64));
  int*      eu         = (int*)     take(NN * sizeof(int));
  int*      ev         = (int*)     take(NN * sizeof(int));
  unsigned* ew         = (unsigned*)take(NN * sizeof(unsigned));
  int*      counters   = (int*)     take(256);
  int*      parent     = (int*)     take(NN * sizeof(int));
  int*      childStart = (int*)     take((NN + 1) * sizeof(int));
  int*      childList  = (int*)     take(NN * sizeof(int));
  int*      levStart   = (int*)     take((NN + 1) * sizeof(int));
  int*      levNodes   = (int*)     take(NN * sizeof(int));
  int*      segList    = (int*)     take(NN * sizeof(int));
  int*      labels     = (int*)     take(NN * sizeof(int));
  int*      meta       = (int*)     take(256);
  float*    w_edge     = (float*)   take(NN * sizeof(float));
  int*      ready      = (int*)     take(NN * sizeof(int));
  int*      cursor     = (int*)     take(256);

  hipLaunchKernelGGL(mrf_init_kernel, dim3((LBL * APITCH + 255) / 256), dim3(256),
                     0, stream, A, Apad, compA, minEa, minEb, counters);

  for (int r = 0; r < MST_ROUNDS; ++r) {
    const int* compR = (r & 1) ? compB : compA;
    int*       compW = (r & 1) ? compA : compB;
    u64*       mcur  = (r & 1) ? minEb : minEa;
    u64*       mnext = (r & 1) ? minEa : minEb;
    hipLaunchKernelGGL(mrf_scan_kernel, dim3(256), dim3(1024), 0, stream,
                       dist, compR, mcur, counters, r);
    hipLaunchKernelGGL(mrf_hook_kernel, dim3(4), dim3(1024), 0, stream,
                       compR, compW, mcur, mnext, eu, ev, ew, counters, r);
  }

  hipLaunchKernelGGL(mrf_root_kernel, dim3(1), dim3(1024), 0, stream,
                     dist, eu, ev, ew, parent, childStart, childList,
                     levStart, levNodes, segList, meta, w_edge,
                     ready, cursor);

  {
    void* args[] = {
      (void*)&unary, (void*)&Apad, (void*)&msgbuf, (void*)&ptrbuf,
      (void*)&parent, (void*)&childStart, (void*)&childList,
      (void*)&levStart, (void*)&levNodes, (void*)&segList, (void*)&w_edge,
      (void*)&labels, (void*)&meta, (void*)&ready, (void*)&cursor
    };
    hipLaunchCooperativeKernel((void*)mrf_solve_kernel, dim3(256), dim3(768),
                               args, 0, stream);
  }

  const int total = NN * LBL;
  hipLaunchKernelGGL(mrf_out_kernel, dim3((total + 255) / 256), dim3(256), 0, stream,
                     labels, out);
}